// Round 14
// baseline (308.088 us; speedup 1.0000x reference)
//
#include <hip/hip_runtime.h>

typedef __attribute__((ext_vector_type(8))) short bf16x8;
typedef __attribute__((ext_vector_type(4))) float f32x4;

constexpr int NB = 16;    // bases
constexpr int REFF = 9;   // relations

struct alignas(8) EPair { float v; int c; };

__device__ __forceinline__ unsigned short f2bf(float f) {
  unsigned u = __float_as_uint(f);
  u += 0x7FFFu + ((u >> 16) & 1u);          // round-to-nearest-even
  return (unsigned short)(u >> 16);
}
__device__ __forceinline__ float bf2f(short s) {
  return __uint_as_float(((unsigned)(unsigned short)s) << 16);
}
__device__ __forceinline__ float bflo(unsigned u) {
  return __uint_as_float(u << 16);
}
__device__ __forceinline__ float bfhi(unsigned u) {
  return __uint_as_float(u & 0xFFFF0000u);
}

// ---------------- merged: histogram + prep (Xbf, W1p, W2p) ----------------
__device__ __forceinline__ unsigned short pack_w_one(const float* __restrict__ comps,
                                                     const float* __restrict__ bases,
                                                     int idx, int NTI, int NTOT) {
  int j = idx & 7;
  int lane = (idx >> 3) & 63;
  int ni = (idx >> 9) % NTI;
  int t = (idx >> 9) / NTI;        // r*8 + ks
  int ks = t & 7;
  int r = t >> 3;
  int k = ks * 32 + ((lane >> 4) << 3) + j;
  int n = ni * 16 + (lane & 15);
  float acc = 0.f;
#pragma unroll
  for (int b = 0; b < NB; ++b)
    acc += comps[r * NB + b] * bases[(size_t)b * 256 * NTOT + (size_t)k * NTOT + n];
  return f2bf(acc);
}

__global__ void hist_prep_kernel(const int* __restrict__ rows,
                                 int* __restrict__ deg1, int E,
                                 const float* __restrict__ features,
                                 unsigned short* __restrict__ Xbf,
                                 const float* __restrict__ comps1,
                                 const float* __restrict__ bases1,
                                 unsigned short* __restrict__ W1p,
                                 const float* __restrict__ comps2,
                                 const float* __restrict__ bases2,
                                 unsigned short* __restrict__ W2p, int N) {
  int idx = blockIdx.x * 256 + threadIdx.x;
  if (idx < E) atomicAdd(&deg1[rows[idx]], 1);
  const int n4 = N * 64;                 // float4 units of features
  const int PW1 = REFF * 8 * 16 * 512;   // 589824
  const int PW2 = REFF * 8 * 2 * 512;    // 73728
  if (idx < n4) {
    float4 f = reinterpret_cast<const float4*>(features)[idx];
    ushort4 o;
    o.x = f2bf(f.x); o.y = f2bf(f.y); o.z = f2bf(f.z); o.w = f2bf(f.w);
    reinterpret_cast<ushort4*>(Xbf)[idx] = o;
  } else if (idx < n4 + PW1) {
    int i = idx - n4;
    W1p[i] = pack_w_one(comps1, bases1, i, 16, 256);
  } else if (idx < n4 + PW1 + PW2) {
    int i = idx - n4 - PW1;
    W2p[i] = pack_w_one(comps2, bases2, i, 2, 32);
  }
}

// ---------------- scan over NR rows (R3-proven 3-pass) ----------------
__global__ void scan1_kernel(const int* __restrict__ deg, int* __restrict__ bsum,
                             int NR) {
  __shared__ int s[256];
  int t = threadIdx.x;
  int base = blockIdx.x * 1024 + t * 4;
  int acc = 0;
#pragma unroll
  for (int q = 0; q < 4; ++q)
    if (base + q < NR) acc += deg[base + q];
  s[t] = acc;
  __syncthreads();
  for (int off = 128; off > 0; off >>= 1) {
    if (t < off) s[t] += s[t + off];
    __syncthreads();
  }
  if (t == 0) bsum[blockIdx.x] = s[0];
}

__global__ void scan2_kernel(int* __restrict__ bsum, int* __restrict__ ptr,
                             int NT, int NR) {
  __shared__ int s[512];
  int t = threadIdx.x;
  int v = (t < NT) ? bsum[t] : 0;
  s[t] = v;
  __syncthreads();
  for (int off = 1; off < 512; off <<= 1) {
    int x = (t >= off) ? s[t - off] : 0;
    __syncthreads();
    s[t] += x;
    __syncthreads();
  }
  if (t < NT) bsum[t] = s[t] - v;          // exclusive
  if (t == NT - 1) ptr[NR] = s[t];
}

__global__ void scan3_kernel(const int* __restrict__ deg,
                             const int* __restrict__ bsum,
                             int* __restrict__ ptr, int NR) {
  __shared__ int s[256];
  int t = threadIdx.x;
  int base = blockIdx.x * 1024 + t * 4;
  int d[4];
#pragma unroll
  for (int q = 0; q < 4; ++q)
    d[q] = (base + q < NR) ? deg[base + q] : 0;
  int tsum = d[0] + d[1] + d[2] + d[3];
  s[t] = tsum;
  __syncthreads();
  for (int off = 1; off < 256; off <<= 1) {
    int x = (t >= off) ? s[t - off] : 0;
    __syncthreads();
    s[t] += x;
    __syncthreads();
  }
  int off0 = bsum[blockIdx.x] + s[t] - tsum;
#pragma unroll
  for (int q = 0; q < 4; ++q) {
    if (base + q < NR) ptr[base + q] = off0;
    off0 += d[q];
  }
}

__global__ void fill_kernel(const int* __restrict__ rows,
                            const int* __restrict__ cols,
                            const float* __restrict__ vals,
                            int* __restrict__ deg1, const int* __restrict__ ptr1,
                            EPair* __restrict__ pay1, int E) {
  int e = blockIdx.x * 256 + threadIdx.x;
  if (e >= E) return;
  int g = rows[e];
  int o1 = atomicSub(&deg1[g], 1);
  EPair pv; pv.v = vals[e]; pv.c = cols[e];
  pay1[ptr1[g] + o1 - 1] = pv;
}

// ---------------- gather: half-wave owns TWO rows as interleaved chains ----------------
// rows rA=unit*2, rB=unit*2+1; both rows' edge loops run together (2x VMEM ILP)
// plus 1-deep pay lookahead on each chain (~4 loads in flight per half-wave).
__device__ __forceinline__ void gather_two_rows(const EPair* __restrict__ pay,
                                                const int* __restrict__ ptr,
                                                const unsigned short* __restrict__ Xbf,
                                                char* lds, int node0, int N, int r,
                                                int unit, int cl) {
  const int rA = unit * 2, rB = rA + 1;
  const int nodeA = node0 + rA;
  float aA[8], aB[8];
#pragma unroll
  for (int j = 0; j < 8; ++j) { aA[j] = 0.f; aB[j] = 0.f; }
  int pA = 0, pAe = 0, pB = 0, pBe = 0;
  {
    int g = r * N + nodeA;
    if (nodeA < N) { pA = ptr[g]; pAe = ptr[g + 1]; }
    if (nodeA + 1 < N) { pB = ptr[g + 1]; pBe = ptr[g + 2]; }
  }
  EPair eA, eB;
  if (pA < pAe) eA = pay[pA];
  if (pB < pBe) eB = pay[pB];
  while (pA < pAe || pB < pBe) {
    bool vA = pA < pAe, vB = pB < pBe;
    bf16x8 xA, xB;
    if (vA) xA = *reinterpret_cast<const bf16x8*>(Xbf + (size_t)eA.c * 256 + cl * 8);
    if (vB) xB = *reinterpret_cast<const bf16x8*>(Xbf + (size_t)eB.c * 256 + cl * 8);
    EPair nA = eA, nB = eB;
    if (vA && pA + 1 < pAe) nA = pay[pA + 1];
    if (vB && pB + 1 < pBe) nB = pay[pB + 1];
    if (vA) {
      float vv = eA.v;
#pragma unroll
      for (int j = 0; j < 8; ++j) aA[j] += vv * bf2f(xA[j]);
      ++pA; eA = nA;
    }
    if (vB) {
      float vv = eB.v;
#pragma unroll
      for (int j = 0; j < 8; ++j) aB[j] += vv * bf2f(xB[j]);
      ++pB; eB = nB;
    }
  }
  uint4 o;
  o.x = (unsigned)f2bf(aA[0]) | ((unsigned)f2bf(aA[1]) << 16);
  o.y = (unsigned)f2bf(aA[2]) | ((unsigned)f2bf(aA[3]) << 16);
  o.z = (unsigned)f2bf(aA[4]) | ((unsigned)f2bf(aA[5]) << 16);
  o.w = (unsigned)f2bf(aA[6]) | ((unsigned)f2bf(aA[7]) << 16);
  *reinterpret_cast<uint4*>(lds + ((rA * 512 + cl * 16) ^ ((rA & 7) << 4))) = o;
  o.x = (unsigned)f2bf(aB[0]) | ((unsigned)f2bf(aB[1]) << 16);
  o.y = (unsigned)f2bf(aB[2]) | ((unsigned)f2bf(aB[3]) << 16);
  o.z = (unsigned)f2bf(aB[4]) | ((unsigned)f2bf(aB[5]) << 16);
  o.w = (unsigned)f2bf(aB[6]) | ((unsigned)f2bf(aB[7]) << 16);
  *reinterpret_cast<uint4*>(lds + ((rB * 512 + cl * 16) ^ ((rB & 7) << 4))) = o;
}

// ---------------- fused layer 1 + layer-2 transform ----------------
// 512 threads / 8 waves; 32-row tile; wave w owns cols [w*32, w*32+32) in L1 MFMA
__global__ __launch_bounds__(512, 8)
void fused_l1(const EPair* __restrict__ pay1, const int* __restrict__ ptr1,
              const unsigned short* __restrict__ Xbf,
              const unsigned short* __restrict__ W1p,
              const float* __restrict__ bias1,
              const unsigned short* __restrict__ W2p,
              unsigned short* __restrict__ Y2, int N) {
  __shared__ char smem[32 * 1024];
  char* lds = smem;                                                  // 16 KB tile
  unsigned short* y2s = reinterpret_cast<unsigned short*>(smem + 16 * 1024); // 16 KB
  const int tid = threadIdx.x;
  const int w = tid >> 6, lane = tid & 63;
  const int l15 = lane & 15, kg = lane >> 4;
  const int unit = tid >> 5, cl = tid & 31;
  const int node0 = blockIdx.x * 32;

  f32x4 acc[2][2];
#pragma unroll
  for (int mi = 0; mi < 2; ++mi)
#pragma unroll
    for (int ni = 0; ni < 2; ++ni) acc[mi][ni] = (f32x4)(0.f);

  for (int r = 0; r < REFF; ++r) {
    gather_two_rows(pay1, ptr1, Xbf, lds, node0, N, r, unit, cl);
    __syncthreads();
#pragma unroll 2
    for (int ks = 0; ks < 8; ++ks) {
      bf16x8 a[2];
#pragma unroll
      for (int mi = 0; mi < 2; ++mi) {
        int row = mi * 16 + l15;
        int boff = (row * 512 + ks * 64 + (kg << 4)) ^ ((row & 7) << 4);
        a[mi] = *reinterpret_cast<const bf16x8*>(lds + boff);
      }
#pragma unroll
      for (int ni = 0; ni < 2; ++ni) {
        int niG = w * 2 + ni;
        bf16x8 b = *reinterpret_cast<const bf16x8*>(
            W1p + (((size_t)(r * 8 + ks) * 16 + niG) << 9) + lane * 8);
#pragma unroll
        for (int mi = 0; mi < 2; ++mi)
          acc[mi][ni] = __builtin_amdgcn_mfma_f32_16x16x32_bf16(a[mi], b,
                                                               acc[mi][ni], 0, 0, 0);
      }
    }
    __syncthreads();
  }

  // epilogue: out1 tile = bf16(relu(acc + bias1)) -> LDS tile (same layout)
#pragma unroll
  for (int mi = 0; mi < 2; ++mi) {
#pragma unroll
    for (int ni = 0; ni < 2; ++ni) {
      int col = (w * 2 + ni) * 16 + l15;
      float bb = bias1[col];
#pragma unroll
      for (int reg = 0; reg < 4; ++reg) {
        int row = mi * 16 + (kg << 2) + reg;
        float v = fmaxf(acc[mi][ni][reg] + bb, 0.f);
        int b = (row * 512 + col * 2) ^ ((row & 7) << 4);
        *reinterpret_cast<unsigned short*>(lds + b) = f2bf(v);
      }
    }
  }
  __syncthreads();

  // layer-2 transform: wave w handles rp = w (wave 0 also rp=8); staged stores
  unsigned short* ys = y2s + w * 1024;   // 2 KB per wave
  for (int rp = w; rp < REFF; rp += 8) {
    f32x4 a2[2][2];   // [mi][nj]
#pragma unroll
    for (int mi = 0; mi < 2; ++mi) {
      a2[mi][0] = (f32x4)(0.f);
      a2[mi][1] = (f32x4)(0.f);
    }
#pragma unroll
    for (int ks = 0; ks < 8; ++ks) {
      bf16x8 b0 = *reinterpret_cast<const bf16x8*>(
          W2p + (((size_t)(rp * 8 + ks) * 2 + 0) << 9) + lane * 8);
      bf16x8 b1 = *reinterpret_cast<const bf16x8*>(
          W2p + (((size_t)(rp * 8 + ks) * 2 + 1) << 9) + lane * 8);
#pragma unroll
      for (int mi = 0; mi < 2; ++mi) {
        int row = mi * 16 + l15;
        int boff = (row * 512 + ks * 64 + (kg << 4)) ^ ((row & 7) << 4);
        bf16x8 a = *reinterpret_cast<const bf16x8*>(lds + boff);
        a2[mi][0] = __builtin_amdgcn_mfma_f32_16x16x32_bf16(a, b0, a2[mi][0], 0, 0, 0);
        a2[mi][1] = __builtin_amdgcn_mfma_f32_16x16x32_bf16(a, b1, a2[mi][1], 0, 0, 0);
      }
    }
    // stage 32x32 bf16 into wave-private LDS, then full-line stores
#pragma unroll
    for (int mi = 0; mi < 2; ++mi)
#pragma unroll
      for (int reg = 0; reg < 4; ++reg) {
        int row16 = mi * 16 + (kg << 2) + reg;
        ys[row16 * 32 + l15] = f2bf(a2[mi][0][reg]);
        ys[row16 * 32 + 16 + l15] = f2bf(a2[mi][1][reg]);
      }
    asm volatile("s_waitcnt lgkmcnt(0)" ::: "memory");
#pragma unroll
    for (int half = 0; half < 2; ++half) {
      int row = half * 16 + (lane >> 2);      // 0..31
      int chunk = lane & 3;                   // 16B chunk within 64B row slice
      uint4 v = *reinterpret_cast<const uint4*>(&ys[row * 32 + chunk * 8]);
      int grow = node0 + row;
      if (grow < N)
        *reinterpret_cast<uint4*>(Y2 + (size_t)grow * (REFF * 32) + rp * 32 + chunk * 8) = v;
    }
  }
}

// ---------------- layer 2 gather off CSR1: out[n] = bias2 + sum_r sum_e v*Y2[src][r] ----------------
__global__ __launch_bounds__(512, 8)
void gather_out_kernel(const EPair* __restrict__ pay1,
                       const int* __restrict__ ptr1,
                       const unsigned short* __restrict__ Y2,
                       const float* __restrict__ bias2,
                       float* __restrict__ out, int N) {
  int wv = threadIdx.x >> 6;
  int lane = threadIdx.x & 63;
  int qw = lane >> 4, c = lane & 15;
  int n = blockIdx.x * 8 + wv;
  if (n >= N) return;
  float ax = 0.f, ay = 0.f;
  for (int r = qw; r < REFF; r += 4) {
    int g = r * N + n;
    int p0 = ptr1[g], p1 = ptr1[g + 1];
    int p = p0;
    for (; p + 2 <= p1; p += 2) {
      EPair e0 = pay1[p];
      EPair e1 = pay1[p + 1];
      unsigned u0 = *reinterpret_cast<const unsigned*>(
          Y2 + (size_t)e0.c * (REFF * 32) + r * 32 + c * 2);
      unsigned u1 = *reinterpret_cast<const unsigned*>(
          Y2 + (size_t)e1.c * (REFF * 32) + r * 32 + c * 2);
      ax += e0.v * bflo(u0) + e1.v * bflo(u1);
      ay += e0.v * bfhi(u0) + e1.v * bfhi(u1);
    }
    if (p < p1) {
      EPair e0 = pay1[p];
      unsigned u0 = *reinterpret_cast<const unsigned*>(
          Y2 + (size_t)e0.c * (REFF * 32) + r * 32 + c * 2);
      ax += e0.v * bflo(u0);
      ay += e0.v * bfhi(u0);
    }
  }
  ax += __shfl_xor(ax, 16); ay += __shfl_xor(ay, 16);
  ax += __shfl_xor(ax, 32); ay += __shfl_xor(ay, 32);
  if (lane < 16) {
    float2 o;
    o.x = ax + bias2[c * 2];
    o.y = ay + bias2[c * 2 + 1];
    reinterpret_cast<float2*>(out)[(size_t)n * 16 + c] = o;
  }
}

extern "C" void kernel_launch(void* const* d_in, const int* in_sizes, int n_in,
                              void* d_out, int out_size, void* d_ws, size_t ws_size,
                              hipStream_t stream) {
  const float* features = (const float*)d_in[0];
  const float* ver_vals = (const float*)d_in[1];
  const float* comps1   = (const float*)d_in[2];
  const float* bases1   = (const float*)d_in[3];
  const float* comps2   = (const float*)d_in[4];
  const float* bases2   = (const float*)d_in[5];
  const float* bias1    = (const float*)d_in[6];
  const float* bias2    = (const float*)d_in[7];
  const int* ver_rows   = (const int*)d_in[8];
  const int* ver_cols   = (const int*)d_in[9];

  const int N = in_sizes[0] / 256;   // 30000
  const int E = in_sizes[1];         // 500000
  const int NR = REFF * N;           // 270000
  const int NT = (NR + 1023) / 1024; // 264

  // ---- workspace layout (~40 MB; 64.1 MB proven-safe) ----
  char* p = (char*)d_ws;
  unsigned short* Xbf = (unsigned short*)p; p += (size_t)N * 256 * 2;        // 15.36 MB
  unsigned short* Y2  = (unsigned short*)p; p += (size_t)N * REFF * 32 * 2;  // 17.28 MB
  unsigned short* W1p = (unsigned short*)p; p += (size_t)REFF * 65536 * 2;   // 1.18 MB
  unsigned short* W2p = (unsigned short*)p; p += (size_t)REFF * 8192 * 2;    // 0.15 MB
  int* ptr1 = (int*)p;     p += (size_t)(NR + 4) * 4;
  EPair* pay1 = (EPair*)p; p += (size_t)E * 8;
  int* deg1 = (int*)p;     p += (size_t)NR * 4;
  int* bsum = (int*)p;     p += 512 * 4;

  // ---- CSR build + prep ----
  hipMemsetAsync(deg1, 0, (size_t)NR * 4, stream);
  const int prep_total = N * 64 + REFF * 8 * 16 * 512 + REFF * 8 * 2 * 512;
  const int hp_grid = ((prep_total > E ? prep_total : E) + 255) / 256;
  hist_prep_kernel<<<hp_grid, 256, 0, stream>>>(ver_rows, deg1, E,
                                                features, Xbf,
                                                comps1, bases1, W1p,
                                                comps2, bases2, W2p, N);
  scan1_kernel<<<NT, 256, 0, stream>>>(deg1, bsum, NR);
  scan2_kernel<<<1, 512, 0, stream>>>(bsum, ptr1, NT, NR);
  scan3_kernel<<<NT, 256, 0, stream>>>(deg1, bsum, ptr1, NR);
  fill_kernel<<<(E + 255) / 256, 256, 0, stream>>>(ver_rows, ver_cols, ver_vals,
                                                   deg1, ptr1, pay1, E);

  // ---- fused layer 1 + layer-2 transform ----
  fused_l1<<<(N + 31) / 32, 512, 0, stream>>>(pay1, ptr1, Xbf, W1p, bias1,
                                              W2p, Y2, N);
  // ---- layer 2 gather ----
  gather_out_kernel<<<(N + 7) / 8, 512, 0, stream>>>(pay1, ptr1, Y2, bias2,
                                                     (float*)d_out, N);
}

// Round 15
// 211.393 us; speedup vs baseline: 1.4574x; 1.4574x over previous
//
#include <hip/hip_runtime.h>

typedef __attribute__((ext_vector_type(8))) short bf16x8;
typedef __attribute__((ext_vector_type(4))) float f32x4;

constexpr int NB = 16;    // bases
constexpr int REFF = 9;   // relations

struct alignas(8) EPair { float v; int c; };

__device__ __forceinline__ unsigned short f2bf(float f) {
  unsigned u = __float_as_uint(f);
  u += 0x7FFFu + ((u >> 16) & 1u);          // round-to-nearest-even
  return (unsigned short)(u >> 16);
}
__device__ __forceinline__ float bf2f(short s) {
  return __uint_as_float(((unsigned)(unsigned short)s) << 16);
}
__device__ __forceinline__ float bflo(unsigned u) {
  return __uint_as_float(u << 16);
}
__device__ __forceinline__ float bfhi(unsigned u) {
  return __uint_as_float(u & 0xFFFF0000u);
}

// ---------------- merged: histogram + prep (Xbf, W1p, W2p) ----------------
__device__ __forceinline__ unsigned short pack_w_one(const float* __restrict__ comps,
                                                     const float* __restrict__ bases,
                                                     int idx, int NTI, int NTOT) {
  int j = idx & 7;
  int lane = (idx >> 3) & 63;
  int ni = (idx >> 9) % NTI;
  int t = (idx >> 9) / NTI;        // r*8 + ks
  int ks = t & 7;
  int r = t >> 3;
  int k = ks * 32 + ((lane >> 4) << 3) + j;
  int n = ni * 16 + (lane & 15);
  float acc = 0.f;
#pragma unroll
  for (int b = 0; b < NB; ++b)
    acc += comps[r * NB + b] * bases[(size_t)b * 256 * NTOT + (size_t)k * NTOT + n];
  return f2bf(acc);
}

__global__ void hist_prep_kernel(const int* __restrict__ rows,
                                 int* __restrict__ deg1, int E,
                                 const float* __restrict__ features,
                                 unsigned short* __restrict__ Xbf,
                                 const float* __restrict__ comps1,
                                 const float* __restrict__ bases1,
                                 unsigned short* __restrict__ W1p,
                                 const float* __restrict__ comps2,
                                 const float* __restrict__ bases2,
                                 unsigned short* __restrict__ W2p, int N) {
  int idx = blockIdx.x * 256 + threadIdx.x;
  if (idx < E) atomicAdd(&deg1[rows[idx]], 1);
  const int n4 = N * 64;                 // float4 units of features
  const int PW1 = REFF * 8 * 16 * 512;   // 589824
  const int PW2 = REFF * 8 * 2 * 512;    // 73728
  if (idx < n4) {
    float4 f = reinterpret_cast<const float4*>(features)[idx];
    ushort4 o;
    o.x = f2bf(f.x); o.y = f2bf(f.y); o.z = f2bf(f.z); o.w = f2bf(f.w);
    reinterpret_cast<ushort4*>(Xbf)[idx] = o;
  } else if (idx < n4 + PW1) {
    int i = idx - n4;
    W1p[i] = pack_w_one(comps1, bases1, i, 16, 256);
  } else if (idx < n4 + PW1 + PW2) {
    int i = idx - n4 - PW1;
    W2p[i] = pack_w_one(comps2, bases2, i, 2, 32);
  }
}

// ---------------- scan over NR rows (R3-proven 3-pass) ----------------
__global__ void scan1_kernel(const int* __restrict__ deg, int* __restrict__ bsum,
                             int NR) {
  __shared__ int s[256];
  int t = threadIdx.x;
  int base = blockIdx.x * 1024 + t * 4;
  int acc = 0;
#pragma unroll
  for (int q = 0; q < 4; ++q)
    if (base + q < NR) acc += deg[base + q];
  s[t] = acc;
  __syncthreads();
  for (int off = 128; off > 0; off >>= 1) {
    if (t < off) s[t] += s[t + off];
    __syncthreads();
  }
  if (t == 0) bsum[blockIdx.x] = s[0];
}

__global__ void scan2_kernel(int* __restrict__ bsum, int* __restrict__ ptr,
                             int NT, int NR) {
  __shared__ int s[512];
  int t = threadIdx.x;
  int v = (t < NT) ? bsum[t] : 0;
  s[t] = v;
  __syncthreads();
  for (int off = 1; off < 512; off <<= 1) {
    int x = (t >= off) ? s[t - off] : 0;
    __syncthreads();
    s[t] += x;
    __syncthreads();
  }
  if (t < NT) bsum[t] = s[t] - v;          // exclusive
  if (t == NT - 1) ptr[NR] = s[t];
}

__global__ void scan3_kernel(const int* __restrict__ deg,
                             const int* __restrict__ bsum,
                             int* __restrict__ ptr, int NR) {
  __shared__ int s[256];
  int t = threadIdx.x;
  int base = blockIdx.x * 1024 + t * 4;
  int d[4];
#pragma unroll
  for (int q = 0; q < 4; ++q)
    d[q] = (base + q < NR) ? deg[base + q] : 0;
  int tsum = d[0] + d[1] + d[2] + d[3];
  s[t] = tsum;
  __syncthreads();
  for (int off = 1; off < 256; off <<= 1) {
    int x = (t >= off) ? s[t - off] : 0;
    __syncthreads();
    s[t] += x;
    __syncthreads();
  }
  int off0 = bsum[blockIdx.x] + s[t] - tsum;
#pragma unroll
  for (int q = 0; q < 4; ++q) {
    if (base + q < NR) ptr[base + q] = off0;
    off0 += d[q];
  }
}

__global__ void fill_kernel(const int* __restrict__ rows,
                            const int* __restrict__ cols,
                            const float* __restrict__ vals,
                            int* __restrict__ deg1, const int* __restrict__ ptr1,
                            EPair* __restrict__ pay1, int E) {
  int e = blockIdx.x * 256 + threadIdx.x;
  if (e >= E) return;
  int g = rows[e];
  int o1 = atomicSub(&deg1[g], 1);
  EPair pv; pv.v = vals[e]; pv.c = cols[e];
  pay1[ptr1[g] + o1 - 1] = pv;
}

// ---------------- gather: half-wave owns a whole row, 1-deep lookahead (R6/R8-proven) ----------------
__device__ __forceinline__ void gather_rows_bf(const EPair* __restrict__ pay,
                                               const int* __restrict__ ptr,
                                               const unsigned short* __restrict__ Xbf,
                                               char* lds, int node0, int N, int r,
                                               int unit, int cl) {
#pragma unroll
  for (int q = 0; q < 2; ++q) {
    int rr = unit * 2 + q;              // row within 32-row tile
    int node = node0 + rr;
    float acc[8];
#pragma unroll
    for (int j = 0; j < 8; ++j) acc[j] = 0.f;
    if (node < N) {
      int g = r * N + node;
      int p0 = ptr[g], p1 = ptr[g + 1];
      EPair e;
      if (p0 < p1) e = pay[p0];
      for (int p = p0; p < p1; ++p) {
        EPair cur = e;
        if (p + 1 < p1) e = pay[p + 1];
        bf16x8 x = *reinterpret_cast<const bf16x8*>(Xbf + (size_t)cur.c * 256 + cl * 8);
#pragma unroll
        for (int j = 0; j < 8; ++j) acc[j] += cur.v * bf2f(x[j]);
      }
    }
    uint4 o;
    o.x = (unsigned)f2bf(acc[0]) | ((unsigned)f2bf(acc[1]) << 16);
    o.y = (unsigned)f2bf(acc[2]) | ((unsigned)f2bf(acc[3]) << 16);
    o.z = (unsigned)f2bf(acc[4]) | ((unsigned)f2bf(acc[5]) << 16);
    o.w = (unsigned)f2bf(acc[6]) | ((unsigned)f2bf(acc[7]) << 16);
    int boff = rr * 512 + cl * 16;
    boff ^= (rr & 7) << 4;              // XOR swizzle (matches reader)
    *reinterpret_cast<uint4*>(lds + boff) = o;
  }
}

// ---------------- fused layer 1 + layer-2 transform ----------------
// 512 threads / 8 waves; 32-row tile; wave w owns cols [w*32, w*32+32) in L1 MFMA
__global__ __launch_bounds__(512, 8)
void fused_l1(const EPair* __restrict__ pay1, const int* __restrict__ ptr1,
              const unsigned short* __restrict__ Xbf,
              const unsigned short* __restrict__ W1p,
              const float* __restrict__ bias1,
              const unsigned short* __restrict__ W2p,
              unsigned short* __restrict__ Y2, int N) {
  __shared__ char smem[32 * 1024];
  char* lds = smem;                                                  // 16 KB tile
  unsigned short* y2s = reinterpret_cast<unsigned short*>(smem + 16 * 1024); // 16 KB
  const int tid = threadIdx.x;
  const int w = tid >> 6, lane = tid & 63;
  const int l15 = lane & 15, kg = lane >> 4;
  const int unit = tid >> 5, cl = tid & 31;
  const int node0 = blockIdx.x * 32;

  f32x4 acc[2][2];
#pragma unroll
  for (int mi = 0; mi < 2; ++mi)
#pragma unroll
    for (int ni = 0; ni < 2; ++ni) acc[mi][ni] = (f32x4)(0.f);

  for (int r = 0; r < REFF; ++r) {
    gather_rows_bf(pay1, ptr1, Xbf, lds, node0, N, r, unit, cl);
    __syncthreads();
#pragma unroll 2
    for (int ks = 0; ks < 8; ++ks) {
      bf16x8 a[2];
#pragma unroll
      for (int mi = 0; mi < 2; ++mi) {
        int row = mi * 16 + l15;
        int boff = (row * 512 + ks * 64 + (kg << 4)) ^ ((row & 7) << 4);
        a[mi] = *reinterpret_cast<const bf16x8*>(lds + boff);
      }
#pragma unroll
      for (int ni = 0; ni < 2; ++ni) {
        int niG = w * 2 + ni;
        bf16x8 b = *reinterpret_cast<const bf16x8*>(
            W1p + (((size_t)(r * 8 + ks) * 16 + niG) << 9) + lane * 8);
#pragma unroll
        for (int mi = 0; mi < 2; ++mi)
          acc[mi][ni] = __builtin_amdgcn_mfma_f32_16x16x32_bf16(a[mi], b,
                                                               acc[mi][ni], 0, 0, 0);
      }
    }
    __syncthreads();
  }

  // epilogue: out1 tile = bf16(relu(acc + bias1)) -> LDS tile (same layout)
#pragma unroll
  for (int mi = 0; mi < 2; ++mi) {
#pragma unroll
    for (int ni = 0; ni < 2; ++ni) {
      int col = (w * 2 + ni) * 16 + l15;
      float bb = bias1[col];
#pragma unroll
      for (int reg = 0; reg < 4; ++reg) {
        int row = mi * 16 + (kg << 2) + reg;
        float v = fmaxf(acc[mi][ni][reg] + bb, 0.f);
        int b = (row * 512 + col * 2) ^ ((row & 7) << 4);
        *reinterpret_cast<unsigned short*>(lds + b) = f2bf(v);
      }
    }
  }
  __syncthreads();

  // layer-2 transform: wave w handles rp = w (wave 0 also rp=8); staged stores
  unsigned short* ys = y2s + w * 1024;   // 2 KB per wave
  for (int rp = w; rp < REFF; rp += 8) {
    f32x4 a2[2][2];   // [mi][nj]
#pragma unroll
    for (int mi = 0; mi < 2; ++mi) {
      a2[mi][0] = (f32x4)(0.f);
      a2[mi][1] = (f32x4)(0.f);
    }
#pragma unroll
    for (int ks = 0; ks < 8; ++ks) {
      bf16x8 b0 = *reinterpret_cast<const bf16x8*>(
          W2p + (((size_t)(rp * 8 + ks) * 2 + 0) << 9) + lane * 8);
      bf16x8 b1 = *reinterpret_cast<const bf16x8*>(
          W2p + (((size_t)(rp * 8 + ks) * 2 + 1) << 9) + lane * 8);
#pragma unroll
      for (int mi = 0; mi < 2; ++mi) {
        int row = mi * 16 + l15;
        int boff = (row * 512 + ks * 64 + (kg << 4)) ^ ((row & 7) << 4);
        bf16x8 a = *reinterpret_cast<const bf16x8*>(lds + boff);
        a2[mi][0] = __builtin_amdgcn_mfma_f32_16x16x32_bf16(a, b0, a2[mi][0], 0, 0, 0);
        a2[mi][1] = __builtin_amdgcn_mfma_f32_16x16x32_bf16(a, b1, a2[mi][1], 0, 0, 0);
      }
    }
    // stage 32x32 bf16 into wave-private LDS, then full-line stores
#pragma unroll
    for (int mi = 0; mi < 2; ++mi)
#pragma unroll
      for (int reg = 0; reg < 4; ++reg) {
        int row16 = mi * 16 + (kg << 2) + reg;
        ys[row16 * 32 + l15] = f2bf(a2[mi][0][reg]);
        ys[row16 * 32 + 16 + l15] = f2bf(a2[mi][1][reg]);
      }
    asm volatile("s_waitcnt lgkmcnt(0)" ::: "memory");
#pragma unroll
    for (int half = 0; half < 2; ++half) {
      int row = half * 16 + (lane >> 2);      // 0..31
      int chunk = lane & 3;                   // 16B chunk within 64B row slice
      uint4 v = *reinterpret_cast<const uint4*>(&ys[row * 32 + chunk * 8]);
      int grow = node0 + row;
      if (grow < N)
        *reinterpret_cast<uint4*>(Y2 + (size_t)grow * (REFF * 32) + rp * 32 + chunk * 8) = v;
    }
  }
}

// ---------------- layer 2 gather off CSR1: out[n] = bias2 + sum_r sum_e v*Y2[src][r] ----------------
__global__ __launch_bounds__(512, 8)
void gather_out_kernel(const EPair* __restrict__ pay1,
                       const int* __restrict__ ptr1,
                       const unsigned short* __restrict__ Y2,
                       const float* __restrict__ bias2,
                       float* __restrict__ out, int N) {
  int wv = threadIdx.x >> 6;
  int lane = threadIdx.x & 63;
  int qw = lane >> 4, c = lane & 15;
  int n = blockIdx.x * 8 + wv;
  if (n >= N) return;
  float ax = 0.f, ay = 0.f;
  for (int r = qw; r < REFF; r += 4) {
    int g = r * N + n;
    int p0 = ptr1[g], p1 = ptr1[g + 1];
    int p = p0;
    for (; p + 2 <= p1; p += 2) {
      EPair e0 = pay1[p];
      EPair e1 = pay1[p + 1];
      unsigned u0 = *reinterpret_cast<const unsigned*>(
          Y2 + (size_t)e0.c * (REFF * 32) + r * 32 + c * 2);
      unsigned u1 = *reinterpret_cast<const unsigned*>(
          Y2 + (size_t)e1.c * (REFF * 32) + r * 32 + c * 2);
      ax += e0.v * bflo(u0) + e1.v * bflo(u1);
      ay += e0.v * bfhi(u0) + e1.v * bfhi(u1);
    }
    if (p < p1) {
      EPair e0 = pay1[p];
      unsigned u0 = *reinterpret_cast<const unsigned*>(
          Y2 + (size_t)e0.c * (REFF * 32) + r * 32 + c * 2);
      ax += e0.v * bflo(u0);
      ay += e0.v * bfhi(u0);
    }
  }
  ax += __shfl_xor(ax, 16); ay += __shfl_xor(ay, 16);
  ax += __shfl_xor(ax, 32); ay += __shfl_xor(ay, 32);
  if (lane < 16) {
    float2 o;
    o.x = ax + bias2[c * 2];
    o.y = ay + bias2[c * 2 + 1];
    reinterpret_cast<float2*>(out)[(size_t)n * 16 + c] = o;
  }
}

extern "C" void kernel_launch(void* const* d_in, const int* in_sizes, int n_in,
                              void* d_out, int out_size, void* d_ws, size_t ws_size,
                              hipStream_t stream) {
  const float* features = (const float*)d_in[0];
  const float* ver_vals = (const float*)d_in[1];
  const float* comps1   = (const float*)d_in[2];
  const float* bases1   = (const float*)d_in[3];
  const float* comps2   = (const float*)d_in[4];
  const float* bases2   = (const float*)d_in[5];
  const float* bias1    = (const float*)d_in[6];
  const float* bias2    = (const float*)d_in[7];
  const int* ver_rows   = (const int*)d_in[8];
  const int* ver_cols   = (const int*)d_in[9];

  const int N = in_sizes[0] / 256;   // 30000
  const int E = in_sizes[1];         // 500000
  const int NR = REFF * N;           // 270000
  const int NT = (NR + 1023) / 1024; // 264

  // ---- workspace layout (~40 MB; 64.1 MB proven-safe) ----
  char* p = (char*)d_ws;
  unsigned short* Xbf = (unsigned short*)p; p += (size_t)N * 256 * 2;        // 15.36 MB
  unsigned short* Y2  = (unsigned short*)p; p += (size_t)N * REFF * 32 * 2;  // 17.28 MB
  unsigned short* W1p = (unsigned short*)p; p += (size_t)REFF * 65536 * 2;   // 1.18 MB
  unsigned short* W2p = (unsigned short*)p; p += (size_t)REFF * 8192 * 2;    // 0.15 MB
  int* ptr1 = (int*)p;     p += (size_t)(NR + 4) * 4;
  EPair* pay1 = (EPair*)p; p += (size_t)E * 8;
  int* deg1 = (int*)p;     p += (size_t)NR * 4;
  int* bsum = (int*)p;     p += 512 * 4;

  // ---- CSR build + prep ----
  hipMemsetAsync(deg1, 0, (size_t)NR * 4, stream);
  const int prep_total = N * 64 + REFF * 8 * 16 * 512 + REFF * 8 * 2 * 512;
  const int hp_grid = ((prep_total > E ? prep_total : E) + 255) / 256;
  hist_prep_kernel<<<hp_grid, 256, 0, stream>>>(ver_rows, deg1, E,
                                                features, Xbf,
                                                comps1, bases1, W1p,
                                                comps2, bases2, W2p, N);
  scan1_kernel<<<NT, 256, 0, stream>>>(deg1, bsum, NR);
  scan2_kernel<<<1, 512, 0, stream>>>(bsum, ptr1, NT, NR);
  scan3_kernel<<<NT, 256, 0, stream>>>(deg1, bsum, ptr1, NR);
  fill_kernel<<<(E + 255) / 256, 256, 0, stream>>>(ver_rows, ver_cols, ver_vals,
                                                   deg1, ptr1, pay1, E);

  // ---- fused layer 1 + layer-2 transform ----
  fused_l1<<<(N + 31) / 32, 512, 0, stream>>>(pay1, ptr1, Xbf, W1p, bias1,
                                              W2p, Y2, N);
  // ---- layer 2 gather ----
  gather_out_kernel<<<(N + 7) / 8, 512, 0, stream>>>(pay1, ptr1, Y2, bias2,
                                                     (float*)d_out, N);
}

// Round 16
// 206.093 us; speedup vs baseline: 1.4949x; 1.0257x over previous
//
#include <hip/hip_runtime.h>

typedef __attribute__((ext_vector_type(8))) short bf16x8;
typedef __attribute__((ext_vector_type(4))) float f32x4;

constexpr int NB = 16;    // bases
constexpr int REFF = 9;   // relations

struct alignas(8) EPair { float v; int c; };

__device__ __forceinline__ unsigned short f2bf(float f) {
  unsigned u = __float_as_uint(f);
  u += 0x7FFFu + ((u >> 16) & 1u);          // round-to-nearest-even
  return (unsigned short)(u >> 16);
}
__device__ __forceinline__ float bf2f(short s) {
  return __uint_as_float(((unsigned)(unsigned short)s) << 16);
}
__device__ __forceinline__ float bflo(unsigned u) {
  return __uint_as_float(u << 16);
}
__device__ __forceinline__ float bfhi(unsigned u) {
  return __uint_as_float(u & 0xFFFF0000u);
}

// ---------------- merged: histogram + prep (Xbf, W1p, W2p) ----------------
__device__ __forceinline__ unsigned short pack_w_one(const float* __restrict__ comps,
                                                     const float* __restrict__ bases,
                                                     int idx, int NTI, int NTOT) {
  int j = idx & 7;
  int lane = (idx >> 3) & 63;
  int ni = (idx >> 9) % NTI;
  int t = (idx >> 9) / NTI;        // r*8 + ks
  int ks = t & 7;
  int r = t >> 3;
  int k = ks * 32 + ((lane >> 4) << 3) + j;
  int n = ni * 16 + (lane & 15);
  float acc = 0.f;
#pragma unroll
  for (int b = 0; b < NB; ++b)
    acc += comps[r * NB + b] * bases[(size_t)b * 256 * NTOT + (size_t)k * NTOT + n];
  return f2bf(acc);
}

__global__ void hist_prep_kernel(const int* __restrict__ rows,
                                 int* __restrict__ deg1, int E,
                                 const float* __restrict__ features,
                                 unsigned short* __restrict__ Xbf,
                                 const float* __restrict__ comps1,
                                 const float* __restrict__ bases1,
                                 unsigned short* __restrict__ W1p,
                                 const float* __restrict__ comps2,
                                 const float* __restrict__ bases2,
                                 unsigned short* __restrict__ W2p, int N) {
  int idx = blockIdx.x * 256 + threadIdx.x;
  if (idx < E) atomicAdd(&deg1[rows[idx]], 1);
  const int n4 = N * 64;                 // float4 units of features
  const int PW1 = REFF * 8 * 16 * 512;   // 589824
  const int PW2 = REFF * 8 * 2 * 512;    // 73728
  if (idx < n4) {
    float4 f = reinterpret_cast<const float4*>(features)[idx];
    ushort4 o;
    o.x = f2bf(f.x); o.y = f2bf(f.y); o.z = f2bf(f.z); o.w = f2bf(f.w);
    reinterpret_cast<ushort4*>(Xbf)[idx] = o;
  } else if (idx < n4 + PW1) {
    int i = idx - n4;
    W1p[i] = pack_w_one(comps1, bases1, i, 16, 256);
  } else if (idx < n4 + PW1 + PW2) {
    int i = idx - n4 - PW1;
    W2p[i] = pack_w_one(comps2, bases2, i, 2, 32);
  }
}

// ---------------- scan over NR rows (R3-proven 3-pass) ----------------
__global__ void scan1_kernel(const int* __restrict__ deg, int* __restrict__ bsum,
                             int NR) {
  __shared__ int s[256];
  int t = threadIdx.x;
  int base = blockIdx.x * 1024 + t * 4;
  int acc = 0;
#pragma unroll
  for (int q = 0; q < 4; ++q)
    if (base + q < NR) acc += deg[base + q];
  s[t] = acc;
  __syncthreads();
  for (int off = 128; off > 0; off >>= 1) {
    if (t < off) s[t] += s[t + off];
    __syncthreads();
  }
  if (t == 0) bsum[blockIdx.x] = s[0];
}

__global__ void scan2_kernel(int* __restrict__ bsum, int* __restrict__ ptr,
                             int NT, int NR) {
  __shared__ int s[512];
  int t = threadIdx.x;
  int v = (t < NT) ? bsum[t] : 0;
  s[t] = v;
  __syncthreads();
  for (int off = 1; off < 512; off <<= 1) {
    int x = (t >= off) ? s[t - off] : 0;
    __syncthreads();
    s[t] += x;
    __syncthreads();
  }
  if (t < NT) bsum[t] = s[t] - v;          // exclusive
  if (t == NT - 1) ptr[NR] = s[t];
}

__global__ void scan3_kernel(const int* __restrict__ deg,
                             const int* __restrict__ bsum,
                             int* __restrict__ ptr, int NR) {
  __shared__ int s[256];
  int t = threadIdx.x;
  int base = blockIdx.x * 1024 + t * 4;
  int d[4];
#pragma unroll
  for (int q = 0; q < 4; ++q)
    d[q] = (base + q < NR) ? deg[base + q] : 0;
  int tsum = d[0] + d[1] + d[2] + d[3];
  s[t] = tsum;
  __syncthreads();
  for (int off = 1; off < 256; off <<= 1) {
    int x = (t >= off) ? s[t - off] : 0;
    __syncthreads();
    s[t] += x;
    __syncthreads();
  }
  int off0 = bsum[blockIdx.x] + s[t] - tsum;
#pragma unroll
  for (int q = 0; q < 4; ++q) {
    if (base + q < NR) ptr[base + q] = off0;
    off0 += d[q];
  }
}

__global__ void fill_kernel(const int* __restrict__ rows,
                            const int* __restrict__ cols,
                            const float* __restrict__ vals,
                            int* __restrict__ deg1, const int* __restrict__ ptr1,
                            EPair* __restrict__ pay1, int E) {
  int e = blockIdx.x * 256 + threadIdx.x;
  if (e >= E) return;
  int g = rows[e];
  int o1 = atomicSub(&deg1[g], 1);
  EPair pv; pv.v = vals[e]; pv.c = cols[e];
  pay1[ptr1[g] + o1 - 1] = pv;
}

// ---------------- gather: half-wave owns a whole row, 1-deep lookahead (R6/R8-proven) ----------------
__device__ __forceinline__ void gather_rows_bf(const EPair* __restrict__ pay,
                                               const int* __restrict__ ptr,
                                               const unsigned short* __restrict__ Xbf,
                                               char* lds, int node0, int N, int r,
                                               int unit, int cl) {
#pragma unroll
  for (int q = 0; q < 2; ++q) {
    int rr = unit * 2 + q;              // row within 32-row tile
    int node = node0 + rr;
    float acc[8];
#pragma unroll
    for (int j = 0; j < 8; ++j) acc[j] = 0.f;
    if (node < N) {
      int g = r * N + node;
      int p0 = ptr[g], p1 = ptr[g + 1];
      EPair e;
      if (p0 < p1) e = pay[p0];
      for (int p = p0; p < p1; ++p) {
        EPair cur = e;
        if (p + 1 < p1) e = pay[p + 1];
        bf16x8 x = *reinterpret_cast<const bf16x8*>(Xbf + (size_t)cur.c * 256 + cl * 8);
#pragma unroll
        for (int j = 0; j < 8; ++j) acc[j] += cur.v * bf2f(x[j]);
      }
    }
    uint4 o;
    o.x = (unsigned)f2bf(acc[0]) | ((unsigned)f2bf(acc[1]) << 16);
    o.y = (unsigned)f2bf(acc[2]) | ((unsigned)f2bf(acc[3]) << 16);
    o.z = (unsigned)f2bf(acc[4]) | ((unsigned)f2bf(acc[5]) << 16);
    o.w = (unsigned)f2bf(acc[6]) | ((unsigned)f2bf(acc[7]) << 16);
    int boff = rr * 512 + cl * 16;
    boff ^= (rr & 7) << 4;              // XOR swizzle (matches reader)
    *reinterpret_cast<uint4*>(lds + boff) = o;
  }
}

// ---------------- fused layer 1 + layer-2 transform (double-buffered A-tile) ----------------
// 512 threads / 8 waves; 32-row tile; wave w owns cols [w*32, w*32+32) in L1 MFMA.
// Schedule: gather(0) -> bar; loop r: { gather(r+1)->buf[(r+1)&1]; MFMA(r)<-buf[r&1]; bar }
// One barrier per relation; gather(r+1) loads overlap MFMA(r).
__global__ __launch_bounds__(512, 8)
void fused_l1(const EPair* __restrict__ pay1, const int* __restrict__ ptr1,
              const unsigned short* __restrict__ Xbf,
              const unsigned short* __restrict__ W1p,
              const float* __restrict__ bias1,
              const unsigned short* __restrict__ W2p,
              unsigned short* __restrict__ Y2, int N) {
  __shared__ char smem[32 * 1024];
  char* bufA = smem;                 // 16 KB tile buffer (even r)
  char* bufB = smem + 16 * 1024;     // 16 KB tile buffer (odd r); y2s after loop
  const int tid = threadIdx.x;
  const int w = tid >> 6, lane = tid & 63;
  const int l15 = lane & 15, kg = lane >> 4;
  const int unit = tid >> 5, cl = tid & 31;
  const int node0 = blockIdx.x * 32;

  f32x4 acc[2][2];
#pragma unroll
  for (int mi = 0; mi < 2; ++mi)
#pragma unroll
    for (int ni = 0; ni < 2; ++ni) acc[mi][ni] = (f32x4)(0.f);

  // prologue: gather relation 0 into bufA
  gather_rows_bf(pay1, ptr1, Xbf, bufA, node0, N, 0, unit, cl);
  __syncthreads();

  for (int r = 0; r < REFF; ++r) {
    char* cur = (r & 1) ? bufB : bufA;
    // issue next relation's gather first (loads overlap this relation's MFMA)
    if (r + 1 < REFF) {
      char* nxt = ((r + 1) & 1) ? bufB : bufA;
      gather_rows_bf(pay1, ptr1, Xbf, nxt, node0, N, r + 1, unit, cl);
    }
    // MFMA phase from cur
#pragma unroll 2
    for (int ks = 0; ks < 8; ++ks) {
      bf16x8 a[2];
#pragma unroll
      for (int mi = 0; mi < 2; ++mi) {
        int row = mi * 16 + l15;
        int boff = (row * 512 + ks * 64 + (kg << 4)) ^ ((row & 7) << 4);
        a[mi] = *reinterpret_cast<const bf16x8*>(cur + boff);
      }
#pragma unroll
      for (int ni = 0; ni < 2; ++ni) {
        int niG = w * 2 + ni;
        bf16x8 b = *reinterpret_cast<const bf16x8*>(
            W1p + (((size_t)(r * 8 + ks) * 16 + niG) << 9) + lane * 8);
#pragma unroll
        for (int mi = 0; mi < 2; ++mi)
          acc[mi][ni] = __builtin_amdgcn_mfma_f32_16x16x32_bf16(a[mi], b,
                                                               acc[mi][ni], 0, 0, 0);
      }
    }
    __syncthreads();
  }

  // epilogue: out1 tile = bf16(relu(acc + bias1)) -> bufA (same swizzled layout)
#pragma unroll
  for (int mi = 0; mi < 2; ++mi) {
#pragma unroll
    for (int ni = 0; ni < 2; ++ni) {
      int col = (w * 2 + ni) * 16 + l15;
      float bb = bias1[col];
#pragma unroll
      for (int reg = 0; reg < 4; ++reg) {
        int row = mi * 16 + (kg << 2) + reg;
        float v = fmaxf(acc[mi][ni][reg] + bb, 0.f);
        int b = (row * 512 + col * 2) ^ ((row & 7) << 4);
        *reinterpret_cast<unsigned short*>(bufA + b) = f2bf(v);
      }
    }
  }
  __syncthreads();

  // layer-2 transform: wave w handles rp = w (wave 0 also rp=8); staged stores via bufB
  unsigned short* ys = reinterpret_cast<unsigned short*>(bufB) + w * 1024;  // 2 KB/wave
  for (int rp = w; rp < REFF; rp += 8) {
    f32x4 a2[2][2];   // [mi][nj]
#pragma unroll
    for (int mi = 0; mi < 2; ++mi) {
      a2[mi][0] = (f32x4)(0.f);
      a2[mi][1] = (f32x4)(0.f);
    }
#pragma unroll
    for (int ks = 0; ks < 8; ++ks) {
      bf16x8 b0 = *reinterpret_cast<const bf16x8*>(
          W2p + (((size_t)(rp * 8 + ks) * 2 + 0) << 9) + lane * 8);
      bf16x8 b1 = *reinterpret_cast<const bf16x8*>(
          W2p + (((size_t)(rp * 8 + ks) * 2 + 1) << 9) + lane * 8);
#pragma unroll
      for (int mi = 0; mi < 2; ++mi) {
        int row = mi * 16 + l15;
        int boff = (row * 512 + ks * 64 + (kg << 4)) ^ ((row & 7) << 4);
        bf16x8 a = *reinterpret_cast<const bf16x8*>(bufA + boff);
        a2[mi][0] = __builtin_amdgcn_mfma_f32_16x16x32_bf16(a, b0, a2[mi][0], 0, 0, 0);
        a2[mi][1] = __builtin_amdgcn_mfma_f32_16x16x32_bf16(a, b1, a2[mi][1], 0, 0, 0);
      }
    }
    // stage 32x32 bf16 into wave-private LDS, then full-line stores
#pragma unroll
    for (int mi = 0; mi < 2; ++mi)
#pragma unroll
      for (int reg = 0; reg < 4; ++reg) {
        int row16 = mi * 16 + (kg << 2) + reg;
        ys[row16 * 32 + l15] = f2bf(a2[mi][0][reg]);
        ys[row16 * 32 + 16 + l15] = f2bf(a2[mi][1][reg]);
      }
    asm volatile("s_waitcnt lgkmcnt(0)" ::: "memory");
#pragma unroll
    for (int half = 0; half < 2; ++half) {
      int row = half * 16 + (lane >> 2);      // 0..31
      int chunk = lane & 3;                   // 16B chunk within 64B row slice
      uint4 v = *reinterpret_cast<const uint4*>(&ys[row * 32 + chunk * 8]);
      int grow = node0 + row;
      if (grow < N)
        *reinterpret_cast<uint4*>(Y2 + (size_t)grow * (REFF * 32) + rp * 32 + chunk * 8) = v;
    }
  }
}

// ---------------- layer 2 gather off CSR1: out[n] = bias2 + sum_r sum_e v*Y2[src][r] ----------------
__global__ __launch_bounds__(512, 8)
void gather_out_kernel(const EPair* __restrict__ pay1,
                       const int* __restrict__ ptr1,
                       const unsigned short* __restrict__ Y2,
                       const float* __restrict__ bias2,
                       float* __restrict__ out, int N) {
  int wv = threadIdx.x >> 6;
  int lane = threadIdx.x & 63;
  int qw = lane >> 4, c = lane & 15;
  int n = blockIdx.x * 8 + wv;
  if (n >= N) return;
  float ax = 0.f, ay = 0.f;
  for (int r = qw; r < REFF; r += 4) {
    int g = r * N + n;
    int p0 = ptr1[g], p1 = ptr1[g + 1];
    int p = p0;
    for (; p + 2 <= p1; p += 2) {
      EPair e0 = pay1[p];
      EPair e1 = pay1[p + 1];
      unsigned u0 = *reinterpret_cast<const unsigned*>(
          Y2 + (size_t)e0.c * (REFF * 32) + r * 32 + c * 2);
      unsigned u1 = *reinterpret_cast<const unsigned*>(
          Y2 + (size_t)e1.c * (REFF * 32) + r * 32 + c * 2);
      ax += e0.v * bflo(u0) + e1.v * bflo(u1);
      ay += e0.v * bfhi(u0) + e1.v * bfhi(u1);
    }
    if (p < p1) {
      EPair e0 = pay1[p];
      unsigned u0 = *reinterpret_cast<const unsigned*>(
          Y2 + (size_t)e0.c * (REFF * 32) + r * 32 + c * 2);
      ax += e0.v * bflo(u0);
      ay += e0.v * bfhi(u0);
    }
  }
  ax += __shfl_xor(ax, 16); ay += __shfl_xor(ay, 16);
  ax += __shfl_xor(ax, 32); ay += __shfl_xor(ay, 32);
  if (lane < 16) {
    float2 o;
    o.x = ax + bias2[c * 2];
    o.y = ay + bias2[c * 2 + 1];
    reinterpret_cast<float2*>(out)[(size_t)n * 16 + c] = o;
  }
}

extern "C" void kernel_launch(void* const* d_in, const int* in_sizes, int n_in,
                              void* d_out, int out_size, void* d_ws, size_t ws_size,
                              hipStream_t stream) {
  const float* features = (const float*)d_in[0];
  const float* ver_vals = (const float*)d_in[1];
  const float* comps1   = (const float*)d_in[2];
  const float* bases1   = (const float*)d_in[3];
  const float* comps2   = (const float*)d_in[4];
  const float* bases2   = (const float*)d_in[5];
  const float* bias1    = (const float*)d_in[6];
  const float* bias2    = (const float*)d_in[7];
  const int* ver_rows   = (const int*)d_in[8];
  const int* ver_cols   = (const int*)d_in[9];

  const int N = in_sizes[0] / 256;   // 30000
  const int E = in_sizes[1];         // 500000
  const int NR = REFF * N;           // 270000
  const int NT = (NR + 1023) / 1024; // 264

  // ---- workspace layout (~40 MB; 64.1 MB proven-safe) ----
  char* p = (char*)d_ws;
  unsigned short* Xbf = (unsigned short*)p; p += (size_t)N * 256 * 2;        // 15.36 MB
  unsigned short* Y2  = (unsigned short*)p; p += (size_t)N * REFF * 32 * 2;  // 17.28 MB
  unsigned short* W1p = (unsigned short*)p; p += (size_t)REFF * 65536 * 2;   // 1.18 MB
  unsigned short* W2p = (unsigned short*)p; p += (size_t)REFF * 8192 * 2;    // 0.15 MB
  int* ptr1 = (int*)p;     p += (size_t)(NR + 4) * 4;
  EPair* pay1 = (EPair*)p; p += (size_t)E * 8;
  int* deg1 = (int*)p;     p += (size_t)NR * 4;
  int* bsum = (int*)p;     p += 512 * 4;

  // ---- CSR build + prep ----
  hipMemsetAsync(deg1, 0, (size_t)NR * 4, stream);
  const int prep_total = N * 64 + REFF * 8 * 16 * 512 + REFF * 8 * 2 * 512;
  const int hp_grid = ((prep_total > E ? prep_total : E) + 255) / 256;
  hist_prep_kernel<<<hp_grid, 256, 0, stream>>>(ver_rows, deg1, E,
                                                features, Xbf,
                                                comps1, bases1, W1p,
                                                comps2, bases2, W2p, N);
  scan1_kernel<<<NT, 256, 0, stream>>>(deg1, bsum, NR);
  scan2_kernel<<<1, 512, 0, stream>>>(bsum, ptr1, NT, NR);
  scan3_kernel<<<NT, 256, 0, stream>>>(deg1, bsum, ptr1, NR);
  fill_kernel<<<(E + 255) / 256, 256, 0, stream>>>(ver_rows, ver_cols, ver_vals,
                                                   deg1, ptr1, pay1, E);

  // ---- fused layer 1 + layer-2 transform ----
  fused_l1<<<(N + 31) / 32, 512, 0, stream>>>(pay1, ptr1, Xbf, W1p, bias1,
                                              W2p, Y2, N);
  // ---- layer 2 gather ----
  gather_out_kernel<<<(N + 7) / 8, 512, 0, stream>>>(pay1, ptr1, Y2, bias2,
                                                     (float*)d_out, N);
}